// Round 1
// baseline (85.387 us; speedup 1.0000x reference)
//
#include <hip/hip_runtime.h>
#include <hip/hip_bf16.h>

// Problem constants (SIMcLoss: x is [8192, 256] fp32, output is 1 fp32 scalar)
#define DCOLS 256
#define TILE 64            // G is 256x256, split into 4x4 tiles of 64x64
#define NTILEP 16          // 4*4 tile pairs
#define CHUNK_ROWS 512     // split-K chunk
#define BATCH 8            // rows staged in LDS per inner iteration
#define EPS 1e-8f

// ---------------------------------------------------------------------------
// Kernel 1: one wave per row -> inv_norm[row] = 1 / max(||x_row||, eps)
// ---------------------------------------------------------------------------
__global__ __launch_bounds__(256) void k_row_inv_norms(
    const float* __restrict__ x, float* __restrict__ inv, int N) {
  int wave = (blockIdx.x * blockDim.x + threadIdx.x) >> 6;
  int lane = threadIdx.x & 63;
  if (wave >= N) return;
  // 64 lanes * float4 = 256 floats = one row, fully coalesced
  const float4 v = reinterpret_cast<const float4*>(x + (size_t)wave * DCOLS)[lane];
  float s = v.x * v.x + v.y * v.y + v.z * v.z + v.w * v.w;
  #pragma unroll
  for (int off = 32; off > 0; off >>= 1) s += __shfl_xor(s, off);
  if (lane == 0) inv[wave] = 1.0f / fmaxf(sqrtf(s), EPS);
}

// ---------------------------------------------------------------------------
// Kernel 2: split-K Gram update. Block (tilepair, chunk) accumulates a 64x64
// tile of G over CHUNK_ROWS rows, then atomicAdds into global G.
// 256 threads as 16x16, each owning a 4x4 register tile.
// ---------------------------------------------------------------------------
__global__ __launch_bounds__(256) void k_gram_splitk(
    const float* __restrict__ x, const float* __restrict__ inv,
    float* __restrict__ G) {
  const int tpair = blockIdx.x;          // 0..15
  const int ta = tpair >> 2;             // A column-tile
  const int tb = tpair & 3;              // B column-tile
  const int row0 = blockIdx.y * CHUNK_ROWS;

  __shared__ float As[BATCH][TILE];
  __shared__ float Bs[BATCH][TILE];

  const int tid = threadIdx.x;
  const int tx = tid & 15;               // -> G columns
  const int ty = tid >> 4;               // -> G rows

  float acc[4][4] = {};

  for (int b0 = 0; b0 < CHUNK_ROWS; b0 += BATCH) {
    // stage BATCH rows x 64 cols for each tile; 512 floats -> 2 per thread
    #pragma unroll
    for (int k = 0; k < 2; ++k) {
      int flat = tid + k * 256;          // 0..511
      int r = flat >> 6, c = flat & 63;
      int row = row0 + b0 + r;
      float in = inv[row];
      const float* xr = x + (size_t)row * DCOLS;
      As[r][c] = xr[ta * TILE + c] * in;
      Bs[r][c] = xr[tb * TILE + c] * in;
    }
    __syncthreads();
    #pragma unroll
    for (int r = 0; r < BATCH; ++r) {
      float4 a = reinterpret_cast<const float4*>(As[r])[ty];
      float4 b = reinterpret_cast<const float4*>(Bs[r])[tx];
      float av[4] = {a.x, a.y, a.z, a.w};
      float bv[4] = {b.x, b.y, b.z, b.w};
      #pragma unroll
      for (int q = 0; q < 4; ++q)
        #pragma unroll
        for (int p = 0; p < 4; ++p)
          acc[q][p] += av[q] * bv[p];
    }
    __syncthreads();
  }

  #pragma unroll
  for (int q = 0; q < 4; ++q) {
    int ga = ta * TILE + ty * 4 + q;
    #pragma unroll
    for (int p = 0; p < 4; ++p) {
      int gb = tb * TILE + tx * 4 + p;
      atomicAdd(&G[ga * DCOLS + gb], acc[q][p]);
    }
  }
}

// ---------------------------------------------------------------------------
// Kernel 3: single block; S = sum(G^2); out = (S - n) / (n^2 - n)
// ---------------------------------------------------------------------------
__global__ __launch_bounds__(256) void k_reduce_loss(
    const float* __restrict__ G, float* __restrict__ out, int N) {
  float s = 0.0f;
  const float4* G4 = reinterpret_cast<const float4*>(G);
  const int n4 = (DCOLS * DCOLS) / 4;    // 16384
  for (int idx = threadIdx.x; idx < n4; idx += 256) {
    float4 v = G4[idx];
    s += v.x * v.x + v.y * v.y + v.z * v.z + v.w * v.w;
  }
  #pragma unroll
  for (int off = 32; off > 0; off >>= 1) s += __shfl_xor(s, off);
  __shared__ float red[4];
  int lane = threadIdx.x & 63, w = threadIdx.x >> 6;
  if (lane == 0) red[w] = s;
  __syncthreads();
  if (threadIdx.x == 0) {
    float S = red[0] + red[1] + red[2] + red[3];
    float nf = (float)N;
    out[0] = (S - nf) / (nf * nf - nf);
  }
}

extern "C" void kernel_launch(void* const* d_in, const int* in_sizes, int n_in,
                              void* d_out, int out_size, void* d_ws, size_t ws_size,
                              hipStream_t stream) {
  const float* x = (const float*)d_in[0];
  float* out = (float*)d_out;
  const int N = in_sizes[0] / DCOLS;     // 8192

  // ws layout: inv_norm[N] | G[256*256]
  float* inv = (float*)d_ws;
  float* G = inv + N;

  // zero the Gram accumulator (harness poisons ws; must zero every call)
  hipMemsetAsync(G, 0, DCOLS * DCOLS * sizeof(float), stream);

  // 1) row inverse norms: one wave per row
  k_row_inv_norms<<<dim3((N * 64 + 255) / 256), dim3(256), 0, stream>>>(x, inv, N);

  // 2) split-K Gram: 16 tile-pairs x 16 chunks = 256 blocks
  k_gram_splitk<<<dim3(NTILEP, N / CHUNK_ROWS), dim3(256), 0, stream>>>(x, inv, G);

  // 3) final reduction to the scalar loss
  k_reduce_loss<<<dim3(1), dim3(256), 0, stream>>>(G, out, N);
}

// Round 2
// 42.371 us; speedup vs baseline: 2.0152x; 2.0152x over previous
//
#include <hip/hip_runtime.h>

// SIMcLoss: x is [8192, 256] fp32 -> scalar fp32.
// S = ||Xn^T Xn||_F^2 computed via symmetric 64x64 block-tiles of the D x D
// Gram matrix (only the 10 upper tiles, off-diagonal tiles weighted 2x).
#define D 256
#define TILE 64
#define NPAIRS 10
#define CHUNK 64          // split-K rows per block
#define BATCH 16          // rows staged in LDS per inner iteration
#define EPS 1e-8f

__device__ __forceinline__ void pair_decode(int p, int& ta, int& tb) {
  if (p < 4)      { ta = 0; tb = p; }
  else if (p < 7) { ta = 1; tb = p - 3; }
  else if (p < 9) { ta = 2; tb = p - 5; }
  else            { ta = 3; tb = 3; }
}

// ---------------------------------------------------------------------------
// Kernel 1: row inverse norms (one wave per row) + zero S/cnt (+ G if atomic)
// ---------------------------------------------------------------------------
__global__ __launch_bounds__(256) void k_prep(
    const float* __restrict__ x, float* __restrict__ inv,
    float* __restrict__ S, unsigned int* __restrict__ cnt,
    float* __restrict__ G, int N, int zero_g) {
  if (blockIdx.x == 0 && threadIdx.x == 0) { *S = 0.0f; *cnt = 0u; }
  if (zero_g && blockIdx.x < 64) {
    reinterpret_cast<float4*>(G)[blockIdx.x * 256 + threadIdx.x] =
        make_float4(0.f, 0.f, 0.f, 0.f);
  }
  int wave = (blockIdx.x * blockDim.x + threadIdx.x) >> 6;
  int lane = threadIdx.x & 63;
  if (wave >= N) return;
  const float4 v = reinterpret_cast<const float4*>(x + (size_t)wave * D)[lane];
  float s = v.x * v.x + v.y * v.y + v.z * v.z + v.w * v.w;
  #pragma unroll
  for (int o = 32; o > 0; o >>= 1) s += __shfl_xor(s, o);
  if (lane == 0) inv[wave] = 1.0f / fmaxf(sqrtf(s), EPS);
}

// ---------------------------------------------------------------------------
// Kernel 2: split-K Gram tiles. grid (10 pairs, N/CHUNK chunks), 256 threads.
// Prefetch next BATCH rows into registers while computing current from LDS.
// Store: private slab (coalesced) if slab mode, else atomicAdd into G.
// ---------------------------------------------------------------------------
__global__ __launch_bounds__(256) void k_gram(
    const float* __restrict__ x, const float* __restrict__ inv,
    float* __restrict__ out_base, int atomic_mode, int nchunk) {
  int ta, tb;
  pair_decode(blockIdx.x, ta, tb);
  const bool same = (ta == tb);
  const int row0 = blockIdx.y * CHUNK;

  __shared__ float As[BATCH][TILE];
  __shared__ float Bs[BATCH][TILE];

  const int tid = threadIdx.x;
  const int r  = tid >> 4;          // 0..15: batch row this thread stages
  const int c  = (tid & 15) << 2;   // 0..60: col group (float4)
  const int tx = tid & 15;          // -> G cols
  const int ty = tid >> 4;          // -> G rows

  // prefetch batch 0
  int row = row0 + r;
  float iv = inv[row];
  const float* xr = x + (size_t)row * D;
  float4 pa = *reinterpret_cast<const float4*>(xr + ta * TILE + c);
  float4 pb;
  if (!same) pb = *reinterpret_cast<const float4*>(xr + tb * TILE + c);

  float acc[4][4] = {};
  const int NIT = CHUNK / BATCH;    // 4

  for (int it = 0; it < NIT; ++it) {
    // commit prefetched batch to LDS (scaled by inv norm)
    *reinterpret_cast<float4*>(&As[r][c]) =
        make_float4(pa.x * iv, pa.y * iv, pa.z * iv, pa.w * iv);
    if (!same)
      *reinterpret_cast<float4*>(&Bs[r][c]) =
          make_float4(pb.x * iv, pb.y * iv, pb.z * iv, pb.w * iv);
    // issue next batch's global loads (latency hides under compute below)
    if (it + 1 < NIT) {
      int nr = row0 + (it + 1) * BATCH + r;
      iv = inv[nr];
      const float* xn = x + (size_t)nr * D;
      pa = *reinterpret_cast<const float4*>(xn + ta * TILE + c);
      if (!same) pb = *reinterpret_cast<const float4*>(xn + tb * TILE + c);
    }
    __syncthreads();
    float (*Bp)[TILE] = same ? As : Bs;
    #pragma unroll
    for (int rr = 0; rr < BATCH; ++rr) {
      float4 a = *reinterpret_cast<const float4*>(&As[rr][ty << 2]);
      float4 b = *reinterpret_cast<const float4*>(&Bp[rr][tx << 2]);
      float av[4] = {a.x, a.y, a.z, a.w};
      float bv[4] = {b.x, b.y, b.z, b.w};
      #pragma unroll
      for (int q = 0; q < 4; ++q)
        #pragma unroll
        for (int pp = 0; pp < 4; ++pp)
          acc[q][pp] = fmaf(av[q], bv[pp], acc[q][pp]);
    }
    __syncthreads();
  }

  if (atomic_mode) {
    float* G = out_base;
    #pragma unroll
    for (int q = 0; q < 4; ++q) {
      int gi = ta * TILE + (ty << 2) + q;
      #pragma unroll
      for (int pp = 0; pp < 4; ++pp)
        atomicAdd(&G[gi * D + tb * TILE + (tx << 2) + pp], acc[q][pp]);
    }
  } else {
    float* slab = out_base +
        ((size_t)blockIdx.x * nchunk + blockIdx.y) * (TILE * TILE);
    #pragma unroll
    for (int q = 0; q < 4; ++q)
      *reinterpret_cast<float4*>(&slab[((ty << 2) + q) * TILE + (tx << 2)]) =
          make_float4(acc[q][0], acc[q][1], acc[q][2], acc[q][3]);
  }
}

// ---------------------------------------------------------------------------
// Kernel 3a (slab): sum slabs per entry, weight, square, global-reduce,
// last block writes the final loss. grid = NPAIRS*64 blocks.
// ---------------------------------------------------------------------------
__global__ __launch_bounds__(256) void k_reduce_slab(
    const float* __restrict__ P, float* __restrict__ S,
    unsigned int* __restrict__ cnt, float* __restrict__ out,
    int nchunk, int N, int nblocks) {
  const int b = blockIdx.x;
  const int p = b >> 6;                        // pair
  const int e = ((b & 63) << 6) + (threadIdx.x & 63);  // entry in 64x64 tile
  const int cg = threadIdx.x >> 6;             // chunk group 0..3 (per wave)

  const float* base = P + ((size_t)p * nchunk + cg) * (TILE * TILE) + e;
  const size_t step = (size_t)4 * TILE * TILE; // stride-4 over chunks
  float s0 = 0.f, s1 = 0.f, s2 = 0.f, s3 = 0.f;
  const int K = nchunk >> 2;                   // chunks per group (32)
  for (int k = 0; k + 3 < K; k += 4) {
    s0 += base[(size_t)(k + 0) * step];
    s1 += base[(size_t)(k + 1) * step];
    s2 += base[(size_t)(k + 2) * step];
    s3 += base[(size_t)(k + 3) * step];
  }
  float s = (s0 + s1) + (s2 + s3);

  __shared__ float sm[4][64];
  sm[cg][threadIdx.x & 63] = s;
  __syncthreads();

  float part = 0.f;
  if (threadIdx.x < 64) {
    int t = threadIdx.x;
    float tot = sm[0][t] + sm[1][t] + sm[2][t] + sm[3][t];
    int ta, tb; pair_decode(p, ta, tb);
    float w = (ta == tb) ? 1.f : 2.f;
    part = w * tot * tot;
    #pragma unroll
    for (int o = 32; o > 0; o >>= 1) part += __shfl_xor(part, o);
    if (t == 0) {
      atomicAdd(S, part);
      __threadfence();
      unsigned int old = atomicAdd(cnt, 1u);
      if (old == (unsigned int)(nblocks - 1)) {
        float Sv = atomicAdd(S, 0.0f);   // coherent read of final sum
        float nf = (float)N;
        out[0] = (Sv - nf) / (nf * nf - nf);
      }
    }
  }
}

// ---------------------------------------------------------------------------
// Kernel 3b (atomic fallback): reduce G directly with tile weights.
// ---------------------------------------------------------------------------
__global__ __launch_bounds__(256) void k_reduce_g(
    const float* __restrict__ G, float* __restrict__ S,
    unsigned int* __restrict__ cnt, float* __restrict__ out,
    int N, int nblocks) {
  int idx = blockIdx.x * 256 + threadIdx.x;    // float4 index, 0..16383
  float4 v = reinterpret_cast<const float4*>(G)[idx];
  int i = idx >> 6;                            // row
  int j = (idx & 63) << 2;                     // first col
  int A = i >> 6, B = j >> 6;
  float w = (A == B) ? 1.f : (A < B ? 2.f : 0.f);
  float part = w * (v.x * v.x + v.y * v.y + v.z * v.z + v.w * v.w);
  #pragma unroll
  for (int o = 32; o > 0; o >>= 1) part += __shfl_xor(part, o);
  __shared__ float red[4];
  int lane = threadIdx.x & 63, wv = threadIdx.x >> 6;
  if (lane == 0) red[wv] = part;
  __syncthreads();
  if (threadIdx.x == 0) {
    float blk = red[0] + red[1] + red[2] + red[3];
    atomicAdd(S, blk);
    __threadfence();
    unsigned int old = atomicAdd(cnt, 1u);
    if (old == (unsigned int)(nblocks - 1)) {
      float Sv = atomicAdd(S, 0.0f);
      float nf = (float)N;
      out[0] = (Sv - nf) / (nf * nf - nf);
    }
  }
}

extern "C" void kernel_launch(void* const* d_in, const int* in_sizes, int n_in,
                              void* d_out, int out_size, void* d_ws, size_t ws_size,
                              hipStream_t stream) {
  const float* x = (const float*)d_in[0];
  float* out = (float*)d_out;
  const int N = in_sizes[0] / D;       // 8192
  const int nchunk = N / CHUNK;        // 128

  // ws layout (floats): inv[N] | S | cnt | pad to +64 | G[256*256] | slabs
  float* inv = (float*)d_ws;
  float* Sp = inv + N;
  unsigned int* cnt = (unsigned int*)(Sp + 1);
  float* G = inv + N + 64;
  float* slabs = G + D * D;
  const size_t need =
      ((size_t)(N + 64 + D * D) + (size_t)NPAIRS * nchunk * TILE * TILE) *
      sizeof(float);
  const bool use_slab = (ws_size >= need);

  k_prep<<<dim3(N / 4), dim3(256), 0, stream>>>(x, inv, Sp, cnt, G, N,
                                                use_slab ? 0 : 1);
  k_gram<<<dim3(NPAIRS, nchunk), dim3(256), 0, stream>>>(
      x, inv, use_slab ? slabs : G, use_slab ? 0 : 1, nchunk);
  if (use_slab) {
    const int nb = NPAIRS * 64;        // 640
    k_reduce_slab<<<dim3(nb), dim3(256), 0, stream>>>(slabs, Sp, cnt, out,
                                                      nchunk, N, nb);
  } else {
    k_reduce_g<<<dim3(64), dim3(256), 0, stream>>>(G, Sp, cnt, out, N, 64);
  }
}

// Round 3
// 39.748 us; speedup vs baseline: 2.1482x; 1.0660x over previous
//
#include <hip/hip_runtime.h>

// SIMcLoss: x [8192, 256] fp32 -> scalar.  S = ||Xn^T Xn||_F^2 via MFMA:
// bf16 hi/lo split, G ~= H^T H + H^T L + L^T H, symmetric 64x64 block-tiles
// (10 upper pairs, off-diag weight 2), split-K over 64-row chunks into slabs.
#define D 256
#define TILE 64
#define NPAIRS 10
#define CHUNK 64
#define EPS 1e-8f

typedef __attribute__((ext_vector_type(8))) short bf16x8;
typedef __attribute__((ext_vector_type(4))) float f32x4;

__device__ __forceinline__ void pair_decode(int p, int& ta, int& tb) {
  if (p < 4)      { ta = 0; tb = p; }
  else if (p < 7) { ta = 1; tb = p - 3; }
  else if (p < 9) { ta = 2; tb = p - 5; }
  else            { ta = 3; tb = 3; }
}

// swizzled short-index into Xt[col][64 rows]: row-stride 64 shorts (128 B).
// XOR bits 3..5 of the row index with g(col): b128 frag reads stay 16B-aligned
// and ~2-way; b64 staging writes stay 8B-aligned and ~4-way.
__device__ __forceinline__ int swz(int col, int r) {
  int g = ((col >> 2) & 7) ^ ((col & 3) << 1);
  return col * 64 + (r ^ (g << 3));
}

// ---------------------------------------------------------------------------
// Kernel 1: row inverse norms (one wave per row) + zero S/cnt (+ G if atomic)
// ---------------------------------------------------------------------------
__global__ __launch_bounds__(256) void k_prep(
    const float* __restrict__ x, float* __restrict__ inv,
    float* __restrict__ S, unsigned int* __restrict__ cnt,
    float* __restrict__ G, int N, int zero_g) {
  if (blockIdx.x == 0 && threadIdx.x == 0) { *S = 0.0f; *cnt = 0u; }
  if (zero_g && blockIdx.x < 64) {
    reinterpret_cast<float4*>(G)[blockIdx.x * 256 + threadIdx.x] =
        make_float4(0.f, 0.f, 0.f, 0.f);
  }
  int wave = (blockIdx.x * blockDim.x + threadIdx.x) >> 6;
  int lane = threadIdx.x & 63;
  if (wave >= N) return;
  const float4 v = reinterpret_cast<const float4*>(x + (size_t)wave * D)[lane];
  float s = v.x * v.x + v.y * v.y + v.z * v.z + v.w * v.w;
  #pragma unroll
  for (int o = 32; o > 0; o >>= 1) s += __shfl_xor(s, o);
  if (lane == 0) inv[wave] = 1.0f / fmaxf(sqrtf(s), EPS);
}

// ---------------------------------------------------------------------------
// Kernel 2: MFMA Gram tiles. grid (10 pairs, N/CHUNK chunks), 256 threads.
// Stage 64 rows x (64|128) cols normalized, hi/lo bf16, TRANSPOSED+swizzled
// in LDS; one barrier; 24 mfma_f32_16x16x32_bf16 per wave; write slab.
// ---------------------------------------------------------------------------
__global__ __launch_bounds__(256) void k_gram(
    const float* __restrict__ x, const float* __restrict__ inv,
    float* __restrict__ out_base, int atomic_mode, int nchunk) {
  int ta, tb; pair_decode(blockIdx.x, ta, tb);
  const bool same = (ta == tb);
  const int row0 = blockIdx.y * CHUNK;

  __shared__ short XH[128 * 64];   // [col][row] swizzled, cols 0..63=A, 64..127=B
  __shared__ short XL[128 * 64];

  const int tid = threadIdx.x;

  // ---- staging: 4x4 micro-transpose per task ----
  const int lcb = same ? 4 : 5;              // log2(col-blocks)
  const int cbm = (1 << lcb) - 1;
  const int ntask = 16 << lcb;               // 256 or 512
  for (int task = tid; task < ntask; task += 256) {
    const int cb = task & cbm, rb = task >> lcb;
    const int c0 = cb << 2;                  // LDS col base
    const int r0 = rb << 2;                  // row base (0..63)
    const int gc0 = (c0 < TILE) ? ta * TILE + c0 : tb * TILE + (c0 - TILE);
    const float4 iv4 = *reinterpret_cast<const float4*>(&inv[row0 + r0]);
    const float ivv[4] = {iv4.x, iv4.y, iv4.z, iv4.w};
    unsigned int hi[4][4], lo[4][4];         // [row jj][col cc]
    #pragma unroll
    for (int jj = 0; jj < 4; ++jj) {
      const float4 v = *reinterpret_cast<const float4*>(
          &x[(size_t)(row0 + r0 + jj) * D + gc0]);
      const float vv[4] = {v.x, v.y, v.z, v.w};
      #pragma unroll
      for (int cc = 0; cc < 4; ++cc) {
        float xn = vv[cc] * ivv[jj];
        unsigned int u = __float_as_uint(xn);
        float hf = __uint_as_float(u & 0xffff0000u);
        float lf = xn - hf;                  // exact
        hi[jj][cc] = u >> 16;
        lo[jj][cc] = __float_as_uint(lf) >> 16;
      }
    }
    #pragma unroll
    for (int cc = 0; cc < 4; ++cc) {
      const int idx = swz(c0 + cc, r0);
      *reinterpret_cast<ushort4*>(&XH[idx]) =
          make_ushort4(hi[0][cc], hi[1][cc], hi[2][cc], hi[3][cc]);
      *reinterpret_cast<ushort4*>(&XL[idx]) =
          make_ushort4(lo[0][cc], lo[1][cc], lo[2][cc], lo[3][cc]);
    }
  }
  __syncthreads();

  // ---- MFMA: wave w owns 32x32 quadrant (i0, j0); 2x2 tiles of 16x16 ----
  const int w = tid >> 6, lane = tid & 63;
  const int i0 = (w >> 1) << 5, j0 = (w & 1) << 5;
  const int lm = lane & 15, lk = lane >> 4;
  const int bbase = same ? 0 : 64;           // B cols live at +64 unless same

  f32x4 zero = {0.f, 0.f, 0.f, 0.f};
  f32x4 acc[2][2] = {{zero, zero}, {zero, zero}};

  #pragma unroll
  for (int r0 = 0; r0 < CHUNK; r0 += 32) {
    const int rbase = r0 + lk * 8;
    bf16x8 Ah[2], Al[2], Bh[2], Bl[2];
    #pragma unroll
    for (int t = 0; t < 2; ++t) {
      const int ia = swz(i0 + t * 16 + lm, rbase);
      Ah[t] = *reinterpret_cast<const bf16x8*>(&XH[ia]);
      Al[t] = *reinterpret_cast<const bf16x8*>(&XL[ia]);
      const int ib = swz(bbase + j0 + t * 16 + lm, rbase);
      Bh[t] = *reinterpret_cast<const bf16x8*>(&XH[ib]);
      Bl[t] = *reinterpret_cast<const bf16x8*>(&XL[ib]);
    }
    #pragma unroll
    for (int it = 0; it < 2; ++it)
      #pragma unroll
      for (int jt = 0; jt < 2; ++jt) {
        acc[it][jt] = __builtin_amdgcn_mfma_f32_16x16x32_bf16(
            Al[it], Bh[jt], acc[it][jt], 0, 0, 0);
        acc[it][jt] = __builtin_amdgcn_mfma_f32_16x16x32_bf16(
            Ah[it], Bl[jt], acc[it][jt], 0, 0, 0);
        acc[it][jt] = __builtin_amdgcn_mfma_f32_16x16x32_bf16(
            Ah[it], Bh[jt], acc[it][jt], 0, 0, 0);
      }
  }

  // ---- epilogue: C/D layout col=lane&15, row=(lane>>4)*4+reg (m89) ----
  if (!atomic_mode) {
    float* slab = out_base +
        ((size_t)blockIdx.x * nchunk + blockIdx.y) * (TILE * TILE);
    #pragma unroll
    for (int it = 0; it < 2; ++it)
      #pragma unroll
      for (int jt = 0; jt < 2; ++jt)
        #pragma unroll
        for (int rg = 0; rg < 4; ++rg)
          slab[(i0 + it * 16 + lk * 4 + rg) * TILE + (j0 + jt * 16 + lm)] =
              acc[it][jt][rg];
  } else {
    float* G = out_base;
    #pragma unroll
    for (int it = 0; it < 2; ++it)
      #pragma unroll
      for (int jt = 0; jt < 2; ++jt)
        #pragma unroll
        for (int rg = 0; rg < 4; ++rg)
          atomicAdd(&G[(ta * TILE + i0 + it * 16 + lk * 4 + rg) * D +
                       tb * TILE + j0 + jt * 16 + lm],
                    acc[it][jt][rg]);
  }
}

// ---------------------------------------------------------------------------
// Kernel 3a (slab): sum slabs per entry, weight, square, global-reduce,
// last block writes the final loss. grid = NPAIRS*64 blocks.
// ---------------------------------------------------------------------------
__global__ __launch_bounds__(256) void k_reduce_slab(
    const float* __restrict__ P, float* __restrict__ S,
    unsigned int* __restrict__ cnt, float* __restrict__ out,
    int nchunk, int N, int nblocks) {
  const int b = blockIdx.x;
  const int p = b >> 6;
  const int e = ((b & 63) << 6) + (threadIdx.x & 63);
  const int cg = threadIdx.x >> 6;

  const float* base = P + ((size_t)p * nchunk + cg) * (TILE * TILE) + e;
  const size_t step = (size_t)4 * TILE * TILE;
  float s0 = 0.f, s1 = 0.f, s2 = 0.f, s3 = 0.f;
  const int K = nchunk >> 2;
  for (int k = 0; k + 3 < K; k += 4) {
    s0 += base[(size_t)(k + 0) * step];
    s1 += base[(size_t)(k + 1) * step];
    s2 += base[(size_t)(k + 2) * step];
    s3 += base[(size_t)(k + 3) * step];
  }
  float s = (s0 + s1) + (s2 + s3);

  __shared__ float sm[4][64];
  sm[cg][threadIdx.x & 63] = s;
  __syncthreads();

  if (threadIdx.x < 64) {
    int t = threadIdx.x;
    float tot = sm[0][t] + sm[1][t] + sm[2][t] + sm[3][t];
    int ta, tb; pair_decode(p, ta, tb);
    float wgt = (ta == tb) ? 1.f : 2.f;
    float part = wgt * tot * tot;
    #pragma unroll
    for (int o = 32; o > 0; o >>= 1) part += __shfl_xor(part, o);
    if (t == 0) {
      atomicAdd(S, part);
      __threadfence();
      unsigned int old = atomicAdd(cnt, 1u);
      if (old == (unsigned int)(nblocks - 1)) {
        float Sv = atomicAdd(S, 0.0f);
        float nf = (float)N;
        out[0] = (Sv - nf) / (nf * nf - nf);
      }
    }
  }
}

// ---------------------------------------------------------------------------
// Kernel 3b (atomic fallback): reduce G directly with tile weights.
// ---------------------------------------------------------------------------
__global__ __launch_bounds__(256) void k_reduce_g(
    const float* __restrict__ G, float* __restrict__ S,
    unsigned int* __restrict__ cnt, float* __restrict__ out,
    int N, int nblocks) {
  int idx = blockIdx.x * 256 + threadIdx.x;
  float4 v = reinterpret_cast<const float4*>(G)[idx];
  int i = idx >> 6;
  int j = (idx & 63) << 2;
  int A = i >> 6, B = j >> 6;
  float wgt = (A == B) ? 1.f : (A < B ? 2.f : 0.f);
  float part = wgt * (v.x * v.x + v.y * v.y + v.z * v.z + v.w * v.w);
  #pragma unroll
  for (int o = 32; o > 0; o >>= 1) part += __shfl_xor(part, o);
  __shared__ float red[4];
  int lane = threadIdx.x & 63, wv = threadIdx.x >> 6;
  if (lane == 0) red[wv] = part;
  __syncthreads();
  if (threadIdx.x == 0) {
    float blk = red[0] + red[1] + red[2] + red[3];
    atomicAdd(S, blk);
    __threadfence();
    unsigned int old = atomicAdd(cnt, 1u);
    if (old == (unsigned int)(nblocks - 1)) {
      float Sv = atomicAdd(S, 0.0f);
      float nf = (float)N;
      out[0] = (Sv - nf) / (nf * nf - nf);
    }
  }
}

extern "C" void kernel_launch(void* const* d_in, const int* in_sizes, int n_in,
                              void* d_out, int out_size, void* d_ws, size_t ws_size,
                              hipStream_t stream) {
  const float* x = (const float*)d_in[0];
  float* out = (float*)d_out;
  const int N = in_sizes[0] / D;       // 8192
  const int nchunk = N / CHUNK;        // 128

  // ws layout (floats): inv[N] | S | cnt | pad to +64 | G[256*256] | slabs
  float* inv = (float*)d_ws;
  float* Sp = inv + N;
  unsigned int* cnt = (unsigned int*)(Sp + 1);
  float* G = inv + N + 64;
  float* slabs = G + D * D;
  const size_t need =
      ((size_t)(N + 64 + D * D) + (size_t)NPAIRS * nchunk * TILE * TILE) *
      sizeof(float);
  const bool use_slab = (ws_size >= need);

  k_prep<<<dim3(N / 4), dim3(256), 0, stream>>>(x, inv, Sp, cnt, G, N,
                                                use_slab ? 0 : 1);
  k_gram<<<dim3(NPAIRS, nchunk), dim3(256), 0, stream>>>(
      x, inv, use_slab ? slabs : G, use_slab ? 0 : 1, nchunk);
  if (use_slab) {
    const int nb = NPAIRS * 64;        // 640
    k_reduce_slab<<<dim3(nb), dim3(256), 0, stream>>>(slabs, Sp, cnt, out,
                                                      nchunk, N, nb);
  } else {
    k_reduce_g<<<dim3(64), dim3(256), 0, stream>>>(G, Sp, cnt, out, N, 64);
  }
}